// Round 8
// baseline (229.636 us; speedup 1.0000x reference)
//
#include <hip/hip_runtime.h>

#define N_NODES 20000
#define HID     256
#define DEG     32
#define TOPK    16

typedef __attribute__((ext_vector_type(8))) short short8;
typedef __attribute__((ext_vector_type(4))) float f32x4;
typedef __attribute__((ext_vector_type(2))) _Float16 half2_t;

__device__ inline unsigned short f2bf(float f) {
    unsigned u = __float_as_uint(f);
    unsigned r = (u + 0x7FFFu + ((u >> 16) & 1u)) >> 16;  // RNE
    return (unsigned short)r;
}
__device__ inline float bf_lo(unsigned u) { return __uint_as_float(u << 16); }
__device__ inline float bf_hi(unsigned u) { return __uint_as_float(u & 0xFFFF0000u); }

__device__ inline unsigned short f2h(float f) {
    _Float16 h = (_Float16)f;               // v_cvt_f16_f32 (RNE)
    return __builtin_bit_cast(unsigned short, h);
}
__device__ inline half2_t u2h2(unsigned u) { return __builtin_bit_cast(half2_t, u); }

__device__ inline ushort4 cvt4(float4 f) {
    ushort4 o;
    o.x = f2bf(f.x); o.y = f2bf(f.y); o.z = f2bf(f.z); o.w = f2bf(f.w);
    return o;
}

// ---------------------------------------------------------------------------
// GEMM accumulate core: 128x128 tile, BK=64, 256 thr (4 waves), mfma 16x16x32.
// W is fp32 (converted to bf16 during staging). A is fp32 (AF32=1) or bf16.
// ---------------------------------------------------------------------------
#define PADE 8
template<int AF32>
__device__ __forceinline__ void gemm_tile_acc(
    const void* __restrict__ Araw, const float* __restrict__ W,
    int M, int rowbase, int colbase, f32x4 acc[4][4])
{
    __shared__ unsigned short As[128][64 + PADE];
    __shared__ unsigned short Ws[128][64 + PADE];

    const int t    = threadIdx.x;
    const int lane = t & 63;
    const int wave = t >> 6;
    const int wm   = (wave & 1) * 64;
    const int wn   = (wave >> 1) * 64;

    const int lm = lane & 15;
    const int q8 = (lane >> 4) * 8;

    for (int k0 = 0; k0 < 256; k0 += 64) {
        #pragma unroll
        for (int cidx = 0; cidx < 4; ++cidx) {
            int idx = t + 256 * cidx;
            int row = idx >> 3;
            int col = (idx & 7) * 8;
            int grow = rowbase + row;
            if (AF32) {
                const float* A = (const float*)Araw;
                float4 f0 = make_float4(0.f, 0.f, 0.f, 0.f);
                float4 f1 = make_float4(0.f, 0.f, 0.f, 0.f);
                if (grow < M) {
                    f0 = *(const float4*)(A + (size_t)grow * 256 + k0 + col);
                    f1 = *(const float4*)(A + (size_t)grow * 256 + k0 + col + 4);
                }
                *(ushort4*)&As[row][col]     = cvt4(f0);
                *(ushort4*)&As[row][col + 4] = cvt4(f1);
            } else {
                const unsigned short* A = (const unsigned short*)Araw;
                uint4 av = make_uint4(0u, 0u, 0u, 0u);
                if (grow < M) av = *(const uint4*)(A + (size_t)grow * 256 + k0 + col);
                *(uint4*)&As[row][col] = av;
            }
            float4 w0 = *(const float4*)(W + (size_t)(colbase + row) * 256 + k0 + col);
            float4 w1 = *(const float4*)(W + (size_t)(colbase + row) * 256 + k0 + col + 4);
            *(ushort4*)&Ws[row][col]     = cvt4(w0);
            *(ushort4*)&Ws[row][col + 4] = cvt4(w1);
        }
        __syncthreads();

        #pragma unroll
        for (int kk = 0; kk < 64; kk += 32) {
            short8 af[4], bfr[4];
            #pragma unroll
            for (int i = 0; i < 4; ++i)
                af[i] = *(const short8*)&As[wm + i * 16 + lm][kk + q8];
            #pragma unroll
            for (int j = 0; j < 4; ++j)
                bfr[j] = *(const short8*)&Ws[wn + j * 16 + lm][kk + q8];
            #pragma unroll
            for (int i = 0; i < 4; ++i)
                #pragma unroll
                for (int j = 0; j < 4; ++j)
                    acc[i][j] = __builtin_amdgcn_mfma_f32_16x16x32_bf16(
                        af[i], bfr[j], acc[i][j], 0, 0, 0);
        }
        __syncthreads();
    }
}

// ---------------------------------------------------------------------------
// q/k/v projections + top-k, one dispatch.
//   blocks 0..959: GEMM, XCD-pinned row-blocks (id&7). A read fp32 directly.
//     q -> fp16 head-major [8][N][32]
//     k -> kv[h][n][0..31]  (fp16)     } one 128B line per (h,n):
//     v -> kv[h][n][32..63] (bf16)     } k-dot and v-gather share lines.
//   blocks 960..3459: top-16 edge-weight mask + normalize (8 nodes/block).
// ---------------------------------------------------------------------------
__global__ __launch_bounds__(256) void gemm_qkv_topk(
    const float* __restrict__ A,
    const float* __restrict__ Wq, const float* __restrict__ Wk,
    const float* __restrict__ Wv,
    const float* __restrict__ bq, const float* __restrict__ bk,
    const float* __restrict__ bv,
    const float* __restrict__ ew,
    unsigned short* __restrict__ Cq, unsigned short* __restrict__ kv,
    float* __restrict__ wgt, int M)
{
    const int id = blockIdx.x;
    const int t  = threadIdx.x;

    if (id >= 960) {                      // ---- topk branch ----
        int n = (id - 960) * 8 + (t >> 5);
        int lane = t & 31;
        float my = ew[n * 32 + lane];
        int cnt = 0;
        #pragma unroll
        for (int j = 0; j < 32; ++j) {
            float o = __shfl(my, j, 32);
            cnt += (o > my || (o == my && j < lane)) ? 1 : 0;
        }
        float w = (cnt < TOPK) ? my : 0.0f;
        float s = w;
        #pragma unroll
        for (int off = 16; off; off >>= 1) s += __shfl_xor(s, off, 32);
        wgt[n * 32 + lane] = w / (s + 1e-5f);
        return;
    }

    const int xcd     = id & 7;
    const int rest    = id >> 3;
    const int rowblk  = xcd + 8 * (rest / 6);
    const int variant = rest % 6;
    if (rowblk >= 157) return;
    const int z  = variant >> 1;
    const int by = variant & 1;

    const float* W    = (z == 0) ? Wq : (z == 1) ? Wk : Wv;
    const float* bias = (z == 0) ? bq : (z == 1) ? bk : bv;

    f32x4 acc[4][4];
    #pragma unroll
    for (int i = 0; i < 4; ++i)
        #pragma unroll
        for (int j = 0; j < 4; ++j)
            acc[i][j] = (f32x4){0.f, 0.f, 0.f, 0.f};

    gemm_tile_acc<1>(A, W, M, rowblk * 128, by * 128, acc);

    const int lane = t & 63;
    const int wave = t >> 6;
    const int wm   = (wave & 1) * 64;
    const int wn   = (wave >> 1) * 64;
    const int lm   = lane & 15;
    const int lq   = lane >> 4;

    #pragma unroll
    for (int j = 0; j < 4; ++j) {
        int col = by * 128 + wn + j * 16 + lm;
        float bv2 = bias[col];
        #pragma unroll
        for (int i = 0; i < 4; ++i) {
            #pragma unroll
            for (int r = 0; r < 4; ++r) {
                int row = rowblk * 128 + wm + i * 16 + lq * 4 + r;
                if (row < M) {
                    float x = acc[i][j][r] + bv2;
                    int hh = col >> 5, cc = col & 31;
                    if (z == 0)
                        Cq[(size_t)hh * ((size_t)N_NODES * 32) + (size_t)row * 32 + cc] = f2h(x);
                    else if (z == 1)
                        kv[(size_t)hh * ((size_t)N_NODES * 64) + (size_t)row * 64 + cc] = f2h(x);
                    else
                        kv[(size_t)hh * ((size_t)N_NODES * 64) + (size_t)row * 64 + 32 + cc] = f2bf(x);
                }
            }
        }
    }
}

// ---------------------------------------------------------------------------
// o-projection: A bf16, Wo fp32 (inline convert), fp32 out + leaky-relu.
// ---------------------------------------------------------------------------
__global__ __launch_bounds__(256) void gemm_out(
    const unsigned short* __restrict__ A, const float* __restrict__ W,
    const float* __restrict__ bias, float* __restrict__ out, int M)
{
    f32x4 acc[4][4];
    #pragma unroll
    for (int i = 0; i < 4; ++i)
        #pragma unroll
        for (int j = 0; j < 4; ++j)
            acc[i][j] = (f32x4){0.f, 0.f, 0.f, 0.f};

    gemm_tile_acc<0>(A, W, M, blockIdx.x * 128, blockIdx.y * 128, acc);

    const int lane = threadIdx.x & 63;
    const int wave = threadIdx.x >> 6;
    const int wm   = (wave & 1) * 64;
    const int wn   = (wave >> 1) * 64;
    const int lm   = lane & 15;
    const int lq   = lane >> 4;

    #pragma unroll
    for (int j = 0; j < 4; ++j) {
        int col = blockIdx.y * 128 + wn + j * 16 + lm;
        float bv2 = bias[col];
        #pragma unroll
        for (int i = 0; i < 4; ++i) {
            #pragma unroll
            for (int r = 0; r < 4; ++r) {
                int row = blockIdx.x * 128 + wm + i * 16 + lq * 4 + r;
                if (row < M) {
                    float x = acc[i][j][r] + bv2;
                    x = (x >= 0.f) ? x : 0.01f * x;
                    out[(size_t)row * 256 + col] = x;
                }
            }
        }
    }
}

// ---------------------------------------------------------------------------
// Attention, head-sharded (head = blockIdx.x & 7 -> XCD-pinned shard).
// kv interleaved [8][N][64]: k fp16 cols 0..31, v bf16 cols 32..63 -> each
// neighbor costs exactly ONE 128B cacheline for both k-dot and v-gather.
// Per-head working set kv 2.56 MB + q 1.28 MB < 4 MiB L2.
// ---------------------------------------------------------------------------
__global__ __launch_bounds__(256) void attn_shard(
    const unsigned short* __restrict__ qh, const unsigned short* __restrict__ kv,
    const int* __restrict__ nbr, const float* __restrict__ wgt,
    unsigned short* __restrict__ agg)
{
    const int h    = blockIdx.x & 7;
    const int t    = threadIdx.x;
    const int lane = t & 31;
    const int n    = (blockIdx.x >> 3) * 8 + (t >> 5);

    const size_t hkv = (size_t)h * ((size_t)N_NODES * 64);
    const size_t hq  = (size_t)h * ((size_t)N_NODES * 32);

    const int   nbv = nbr[n * 32 + lane];
    const float w   = wgt[n * 32 + lane];

    const int cg = lane & 7;
    const int dg = lane >> 3;

    // ---- v prefetch: 8 x uint2 (4 bf16 cols) for neighbors dg+4j;
    //      pulls the kv line that the k-dot below will reuse ----
    int nbj[8];
    #pragma unroll
    for (int j = 0; j < 8; ++j)
        nbj[j] = __shfl(nbv, dg + 4 * j, 32);
    uint2 vreg[8];
    #pragma unroll
    for (int j = 0; j < 8; ++j)
        vreg[j] = *(const uint2*)(kv + hkv + (size_t)nbj[j] * 64 + 32 + cg * 4);

    // ---- score: k row (own neighbor) . q row, fp16, 16x fdot2 ----
    const unsigned short* kp = kv + hkv + (size_t)nbv * 64;
    const unsigned short* qp = qh + hq + (size_t)n * 32;

    float sc = 0.f;
    #pragma unroll
    for (int m = 0; m < 4; ++m) {
        uint4 kr = *(const uint4*)(kp + m * 8);
        uint4 qr = *(const uint4*)(qp + m * 8);
        sc = __builtin_amdgcn_fdot2(u2h2(kr.x), u2h2(qr.x), sc, false);
        sc = __builtin_amdgcn_fdot2(u2h2(kr.y), u2h2(qr.y), sc, false);
        sc = __builtin_amdgcn_fdot2(u2h2(kr.z), u2h2(qr.z), sc, false);
        sc = __builtin_amdgcn_fdot2(u2h2(kr.w), u2h2(qr.w), sc, false);
    }

    float logit = sc * w * 0.17677669529663687f;  // * w / sqrt(32)

    float mx = logit;
    #pragma unroll
    for (int off = 16; off; off >>= 1) mx = fmaxf(mx, __shfl_xor(mx, off, 32));
    float e = expf(logit - mx);
    float ssum = e;
    #pragma unroll
    for (int off = 16; off; off >>= 1) ssum += __shfl_xor(ssum, off, 32);
    const float att = e / ssum;

    // ---- v accumulate: 4 cols x 8 neighbors ----
    float a0 = 0.f, a1 = 0.f, a2 = 0.f, a3 = 0.f;
    #pragma unroll
    for (int j = 0; j < 8; ++j) {
        float aw = __shfl(att, dg + 4 * j, 32);
        uint2 vv = vreg[j];
        a0 = fmaf(aw, bf_lo(vv.x), a0);
        a1 = fmaf(aw, bf_hi(vv.x), a1);
        a2 = fmaf(aw, bf_lo(vv.y), a2);
        a3 = fmaf(aw, bf_hi(vv.y), a3);
    }
    a0 += __shfl_xor(a0, 8, 32);  a0 += __shfl_xor(a0, 16, 32);
    a1 += __shfl_xor(a1, 8, 32);  a1 += __shfl_xor(a1, 16, 32);
    a2 += __shfl_xor(a2, 8, 32);  a2 += __shfl_xor(a2, 16, 32);
    a3 += __shfl_xor(a3, 8, 32);  a3 += __shfl_xor(a3, 16, 32);

    if (dg == 0) {
        ushort4 o;
        o.x = f2bf(a0); o.y = f2bf(a1); o.z = f2bf(a2); o.w = f2bf(a3);
        *(ushort4*)(agg + (size_t)n * 256 + h * 32 + cg * 4) = o;
    }
}

// ---------------------------------------------------------------------------
extern "C" void kernel_launch(void* const* d_in, const int* in_sizes, int n_in,
                              void* d_out, int out_size, void* d_ws, size_t ws_size,
                              hipStream_t stream)
{
    const float* h   = (const float*)d_in[0];
    const int*   nbr = (const int*)  d_in[1];
    const float* ew  = (const float*)d_in[2];
    const float* Wq  = (const float*)d_in[3];
    const float* bq  = (const float*)d_in[4];
    const float* Wk  = (const float*)d_in[5];
    const float* bk  = (const float*)d_in[6];
    const float* Wv  = (const float*)d_in[7];
    const float* bv  = (const float*)d_in[8];
    const float* Wo  = (const float*)d_in[9];
    const float* bo  = (const float*)d_in[10];
    float* out = (float*)d_out;

    const size_t NM = (size_t)N_NODES * HID;   // 5,120,000
    char* ws = (char*)d_ws;
    unsigned short* qb   = (unsigned short*)ws; ws += NM * 2;       // fp16 [8][N][32]
    unsigned short* kvb  = (unsigned short*)ws; ws += NM * 4;       // [8][N][64] k fp16 | v bf16
    unsigned short* aggb = (unsigned short*)ws; ws += NM * 2;       // bf16 [N][256]
    float* wgt = (float*)ws;                    ws += (size_t)N_NODES * 32 * 4;

    dim3 blk(256);

    gemm_qkv_topk<<<dim3(3460), blk, 0, stream>>>(h, Wq, Wk, Wv, bq, bk, bv, ew,
                                                  qb, kvb, wgt, N_NODES);

    attn_shard<<<dim3(20000), blk, 0, stream>>>(qb, kvb, nbr, wgt, aggb);

    gemm_out<<<dim3(157, 2), blk, 0, stream>>>(aggb, Wo, bo, out, N_NODES);
}

// Round 9
// 184.440 us; speedup vs baseline: 1.2450x; 1.2450x over previous
//
#include <hip/hip_runtime.h>

#define N_NODES 20000
#define HID     256
#define DEG     32
#define TOPK    16

typedef __attribute__((ext_vector_type(8))) short short8;
typedef __attribute__((ext_vector_type(4))) float f32x4;
typedef __attribute__((ext_vector_type(2))) _Float16 half2_t;

__device__ inline unsigned short f2bf(float f) {
    unsigned u = __float_as_uint(f);
    unsigned r = (u + 0x7FFFu + ((u >> 16) & 1u)) >> 16;  // RNE
    return (unsigned short)r;
}
__device__ inline float bf_lo(unsigned u) { return __uint_as_float(u << 16); }
__device__ inline float bf_hi(unsigned u) { return __uint_as_float(u & 0xFFFF0000u); }

__device__ inline unsigned short f2h(float f) {
    _Float16 h = (_Float16)f;               // v_cvt_f16_f32 (RNE)
    return __builtin_bit_cast(unsigned short, h);
}
__device__ inline half2_t u2h2(unsigned u) { return __builtin_bit_cast(half2_t, u); }

__device__ inline ushort4 cvt4(float4 f) {
    ushort4 o;
    o.x = f2bf(f.x); o.y = f2bf(f.y); o.z = f2bf(f.z); o.w = f2bf(f.w);
    return o;
}

// ---------------------------------------------------------------------------
// GEMM accumulate core: 128x128 tile, BK=64, 256 thr (4 waves), mfma 16x16x32.
// OPERAND-SWAPPED: mfma(W-frag, A-frag) so D col = node row, D reg-dim = 4
// consecutive output cols -> vectorized epilogue stores.
// W fp32 (converted during staging). A fp32 (AF32=1) or bf16.
// ---------------------------------------------------------------------------
#define PADE 8
template<int AF32>
__device__ __forceinline__ void gemm_tile_acc(
    const void* __restrict__ Araw, const float* __restrict__ W,
    int M, int rowbase, int colbase, f32x4 acc[4][4])
{
    __shared__ unsigned short As[128][64 + PADE];
    __shared__ unsigned short Ws[128][64 + PADE];

    const int t    = threadIdx.x;
    const int lane = t & 63;
    const int wave = t >> 6;
    const int wm   = (wave & 1) * 64;
    const int wn   = (wave >> 1) * 64;

    const int lm = lane & 15;
    const int q8 = (lane >> 4) * 8;

    for (int k0 = 0; k0 < 256; k0 += 64) {
        #pragma unroll
        for (int cidx = 0; cidx < 4; ++cidx) {
            int idx = t + 256 * cidx;
            int row = idx >> 3;
            int col = (idx & 7) * 8;
            int grow = rowbase + row;
            if (AF32) {
                const float* A = (const float*)Araw;
                float4 f0 = make_float4(0.f, 0.f, 0.f, 0.f);
                float4 f1 = make_float4(0.f, 0.f, 0.f, 0.f);
                if (grow < M) {
                    f0 = *(const float4*)(A + (size_t)grow * 256 + k0 + col);
                    f1 = *(const float4*)(A + (size_t)grow * 256 + k0 + col + 4);
                }
                *(ushort4*)&As[row][col]     = cvt4(f0);
                *(ushort4*)&As[row][col + 4] = cvt4(f1);
            } else {
                const unsigned short* A = (const unsigned short*)Araw;
                uint4 av = make_uint4(0u, 0u, 0u, 0u);
                if (grow < M) av = *(const uint4*)(A + (size_t)grow * 256 + k0 + col);
                *(uint4*)&As[row][col] = av;
            }
            float4 w0 = *(const float4*)(W + (size_t)(colbase + row) * 256 + k0 + col);
            float4 w1 = *(const float4*)(W + (size_t)(colbase + row) * 256 + k0 + col + 4);
            *(ushort4*)&Ws[row][col]     = cvt4(w0);
            *(ushort4*)&Ws[row][col + 4] = cvt4(w1);
        }
        __syncthreads();

        #pragma unroll
        for (int kk = 0; kk < 64; kk += 32) {
            short8 af[4], bfr[4];
            #pragma unroll
            for (int i = 0; i < 4; ++i)
                af[i] = *(const short8*)&As[wm + i * 16 + lm][kk + q8];
            #pragma unroll
            for (int j = 0; j < 4; ++j)
                bfr[j] = *(const short8*)&Ws[wn + j * 16 + lm][kk + q8];
            #pragma unroll
            for (int i = 0; i < 4; ++i)
                #pragma unroll
                for (int j = 0; j < 4; ++j)
                    acc[i][j] = __builtin_amdgcn_mfma_f32_16x16x32_bf16(
                        bfr[j], af[i], acc[i][j], 0, 0, 0);   // SWAPPED operands
        }
        __syncthreads();
    }
}

// ---------------------------------------------------------------------------
// q/k/v projections + top-k, one dispatch.
//   blocks 0..959: GEMM, XCD-pinned row-blocks (id&7). A read fp32 directly.
//     q  -> fp16 head-major [8][N][32]
//     kv -> [8][N][64], 16B chunks: chunk c = {k[4c..4c+3] fp16, v[4c..4c+3] bf16}
//   blocks 960..3459: top-16 edge-weight mask + normalize (8 nodes/block).
// Epilogue: node = D col (lane&15), 4 consecutive out cols per acc -> 8B stores.
// ---------------------------------------------------------------------------
__global__ __launch_bounds__(256) void gemm_qkv_topk(
    const float* __restrict__ A,
    const float* __restrict__ Wq, const float* __restrict__ Wk,
    const float* __restrict__ Wv,
    const float* __restrict__ bq, const float* __restrict__ bk,
    const float* __restrict__ bv,
    const float* __restrict__ ew,
    unsigned short* __restrict__ Cq, unsigned short* __restrict__ kv,
    float* __restrict__ wgt, int M)
{
    const int id = blockIdx.x;
    const int t  = threadIdx.x;

    if (id >= 960) {                      // ---- topk branch ----
        int n = (id - 960) * 8 + (t >> 5);
        int lane = t & 31;
        float my = ew[n * 32 + lane];
        int cnt = 0;
        #pragma unroll
        for (int j = 0; j < 32; ++j) {
            float o = __shfl(my, j, 32);
            cnt += (o > my || (o == my && j < lane)) ? 1 : 0;
        }
        float w = (cnt < TOPK) ? my : 0.0f;
        float s = w;
        #pragma unroll
        for (int off = 16; off; off >>= 1) s += __shfl_xor(s, off, 32);
        wgt[n * 32 + lane] = w / (s + 1e-5f);
        return;
    }

    const int xcd     = id & 7;
    const int rest    = id >> 3;
    const int rowblk  = xcd + 8 * (rest / 6);
    const int variant = rest % 6;
    if (rowblk >= 157) return;
    const int z  = variant >> 1;
    const int by = variant & 1;

    const float* W    = (z == 0) ? Wq : (z == 1) ? Wk : Wv;
    const float* bias = (z == 0) ? bq : (z == 1) ? bk : bv;

    f32x4 acc[4][4];
    #pragma unroll
    for (int i = 0; i < 4; ++i)
        #pragma unroll
        for (int j = 0; j < 4; ++j)
            acc[i][j] = (f32x4){0.f, 0.f, 0.f, 0.f};

    gemm_tile_acc<1>(A, W, M, rowblk * 128, by * 128, acc);

    const int lane = t & 63;
    const int wave = t >> 6;
    const int wm   = (wave & 1) * 64;
    const int wn   = (wave >> 1) * 64;
    const int lm   = lane & 15;
    const int lq   = lane >> 4;

    #pragma unroll
    for (int i = 0; i < 4; ++i) {
        int node = rowblk * 128 + wm + i * 16 + lm;
        if (node >= M) continue;
        #pragma unroll
        for (int j = 0; j < 4; ++j) {
            int col0 = by * 128 + wn + j * 16 + lq * 4;   // 4 consecutive cols
            float4 b4 = *(const float4*)(bias + col0);
            float x0 = acc[i][j][0] + b4.x;
            float x1 = acc[i][j][1] + b4.y;
            float x2 = acc[i][j][2] + b4.z;
            float x3 = acc[i][j][3] + b4.w;
            int hh = col0 >> 5, cc = col0 & 31;
            if (z == 0) {
                ushort4 o; o.x = f2h(x0); o.y = f2h(x1); o.z = f2h(x2); o.w = f2h(x3);
                *(ushort4*)(Cq + (size_t)hh * ((size_t)N_NODES * 32)
                               + (size_t)node * 32 + cc) = o;
            } else if (z == 1) {
                ushort4 o; o.x = f2h(x0); o.y = f2h(x1); o.z = f2h(x2); o.w = f2h(x3);
                *(ushort4*)(kv + (size_t)hh * ((size_t)N_NODES * 64)
                               + (size_t)node * 64 + (cc >> 2) * 8) = o;
            } else {
                ushort4 o; o.x = f2bf(x0); o.y = f2bf(x1); o.z = f2bf(x2); o.w = f2bf(x3);
                *(ushort4*)(kv + (size_t)hh * ((size_t)N_NODES * 64)
                               + (size_t)node * 64 + (cc >> 2) * 8 + 4) = o;
            }
        }
    }
}

// ---------------------------------------------------------------------------
// o-projection: A bf16, Wo fp32 (inline convert), fp32 out + leaky-relu.
// Swapped epilogue: float4 stores.
// ---------------------------------------------------------------------------
__global__ __launch_bounds__(256) void gemm_out(
    const unsigned short* __restrict__ A, const float* __restrict__ W,
    const float* __restrict__ bias, float* __restrict__ out, int M)
{
    f32x4 acc[4][4];
    #pragma unroll
    for (int i = 0; i < 4; ++i)
        #pragma unroll
        for (int j = 0; j < 4; ++j)
            acc[i][j] = (f32x4){0.f, 0.f, 0.f, 0.f};

    gemm_tile_acc<0>(A, W, M, blockIdx.x * 128, blockIdx.y * 128, acc);

    const int lane = threadIdx.x & 63;
    const int wave = threadIdx.x >> 6;
    const int wm   = (wave & 1) * 64;
    const int wn   = (wave >> 1) * 64;
    const int lm   = lane & 15;
    const int lq   = lane >> 4;

    #pragma unroll
    for (int i = 0; i < 4; ++i) {
        int node = blockIdx.x * 128 + wm + i * 16 + lm;
        if (node >= M) continue;
        #pragma unroll
        for (int j = 0; j < 4; ++j) {
            int col0 = blockIdx.y * 128 + wn + j * 16 + lq * 4;
            float4 b4 = *(const float4*)(bias + col0);
            float4 o;
            o.x = acc[i][j][0] + b4.x;
            o.y = acc[i][j][1] + b4.y;
            o.z = acc[i][j][2] + b4.z;
            o.w = acc[i][j][3] + b4.w;
            o.x = (o.x >= 0.f) ? o.x : 0.01f * o.x;
            o.y = (o.y >= 0.f) ? o.y : 0.01f * o.y;
            o.z = (o.z >= 0.f) ? o.z : 0.01f * o.z;
            o.w = (o.w >= 0.f) ? o.w : 0.01f * o.w;
            *(float4*)(out + (size_t)node * 256 + col0) = o;
        }
    }
}

// ---------------------------------------------------------------------------
// Attention, head-sharded (head = blockIdx.x & 7 -> XCD-pinned shard).
// kv [8][N][64] in 16B chunks {4 k fp16 | 4 v bf16}. 32-lane group per node:
// lane (cg=lane&7, dg=lane>>3) handles chunk cg of neighbors dg+4j (j=0..7).
// EVERY gather instruction is fully coalesced: 8 lanes cover a 128B kv row.
// Partial k-dots reduced over cg (xor 1,2,4); softmax stats over dg (xor 8,16).
// ---------------------------------------------------------------------------
__global__ __launch_bounds__(256) void attn_shard(
    const unsigned short* __restrict__ qh, const unsigned short* __restrict__ kv,
    const int* __restrict__ nbr, const float* __restrict__ wgt,
    unsigned short* __restrict__ agg)
{
    const int h    = blockIdx.x & 7;
    const int t    = threadIdx.x;
    const int lane = t & 31;
    const int n    = (blockIdx.x >> 3) * 8 + (t >> 5);

    const size_t hkv = (size_t)h * ((size_t)N_NODES * 64);
    const size_t hq  = (size_t)h * ((size_t)N_NODES * 32);

    const int   nbv = nbr[n * 32 + lane];
    const float w   = wgt[n * 32 + lane];

    const int cg = lane & 7;
    const int dg = lane >> 3;            // 0..3

    // neighbors this lane covers: dg + 4j
    int   nbj[8];
    float wj[8];
    #pragma unroll
    for (int j = 0; j < 8; ++j) {
        nbj[j] = __shfl(nbv, dg + 4 * j, 32);
        wj[j]  = __shfl(w,   dg + 4 * j, 32);
    }

    // one fully-coalesced uint4 per neighbor: chunk cg = 4 k fp16 + 4 v bf16
    uint4 kvr[8];
    #pragma unroll
    for (int j = 0; j < 8; ++j)
        kvr[j] = *(const uint4*)(kv + hkv + (size_t)nbj[j] * 64 + cg * 8);

    // q chunk: 4 fp16 at cols 4cg..4cg+3 (broadcast across dg)
    uint2 qc = *(const uint2*)(qh + hq + (size_t)n * 32 + cg * 4);

    // partial scores (4 cols), reduce over cg
    float p[8];
    #pragma unroll
    for (int j = 0; j < 8; ++j) {
        float s = __builtin_amdgcn_fdot2(u2h2(kvr[j].x), u2h2(qc.x), 0.f, false);
        p[j]    = __builtin_amdgcn_fdot2(u2h2(kvr[j].y), u2h2(qc.y), s, false);
    }
    #pragma unroll
    for (int off = 1; off <= 4; off <<= 1)
        #pragma unroll
        for (int j = 0; j < 8; ++j)
            p[j] += __shfl_xor(p[j], off, 32);

    // logits, softmax over the 32 neighbors (8 local x 4 dg)
    #pragma unroll
    for (int j = 0; j < 8; ++j)
        p[j] = p[j] * wj[j] * 0.17677669529663687f;   // * w / sqrt(32)

    float mx = p[0];
    #pragma unroll
    for (int j = 1; j < 8; ++j) mx = fmaxf(mx, p[j]);
    mx = fmaxf(mx, __shfl_xor(mx, 8, 32));
    mx = fmaxf(mx, __shfl_xor(mx, 16, 32));

    float ssum = 0.f;
    #pragma unroll
    for (int j = 0; j < 8; ++j) {
        p[j] = expf(p[j] - mx);
        ssum += p[j];
    }
    ssum += __shfl_xor(ssum, 8, 32);
    ssum += __shfl_xor(ssum, 16, 32);
    const float inv = 1.0f / ssum;

    // v accumulate: cols 4cg..4cg+3, partial over dg then reduce (xor 8,16)
    float a0 = 0.f, a1 = 0.f, a2 = 0.f, a3 = 0.f;
    #pragma unroll
    for (int j = 0; j < 8; ++j) {
        float aw = p[j] * inv;
        a0 = fmaf(aw, bf_lo(kvr[j].z), a0);
        a1 = fmaf(aw, bf_hi(kvr[j].z), a1);
        a2 = fmaf(aw, bf_lo(kvr[j].w), a2);
        a3 = fmaf(aw, bf_hi(kvr[j].w), a3);
    }
    a0 += __shfl_xor(a0, 8, 32);  a0 += __shfl_xor(a0, 16, 32);
    a1 += __shfl_xor(a1, 8, 32);  a1 += __shfl_xor(a1, 16, 32);
    a2 += __shfl_xor(a2, 8, 32);  a2 += __shfl_xor(a2, 16, 32);
    a3 += __shfl_xor(a3, 8, 32);  a3 += __shfl_xor(a3, 16, 32);

    if (dg == 0) {
        ushort4 o;
        o.x = f2bf(a0); o.y = f2bf(a1); o.z = f2bf(a2); o.w = f2bf(a3);
        *(ushort4*)(agg + (size_t)n * 256 + h * 32 + cg * 4) = o;
    }
}

// ---------------------------------------------------------------------------
extern "C" void kernel_launch(void* const* d_in, const int* in_sizes, int n_in,
                              void* d_out, int out_size, void* d_ws, size_t ws_size,
                              hipStream_t stream)
{
    const float* h   = (const float*)d_in[0];
    const int*   nbr = (const int*)  d_in[1];
    const float* ew  = (const float*)d_in[2];
    const float* Wq  = (const float*)d_in[3];
    const float* bq  = (const float*)d_in[4];
    const float* Wk  = (const float*)d_in[5];
    const float* bk  = (const float*)d_in[6];
    const float* Wv  = (const float*)d_in[7];
    const float* bv  = (const float*)d_in[8];
    const float* Wo  = (const float*)d_in[9];
    const float* bo  = (const float*)d_in[10];
    float* out = (float*)d_out;

    const size_t NM = (size_t)N_NODES * HID;   // 5,120,000
    char* ws = (char*)d_ws;
    unsigned short* qb   = (unsigned short*)ws; ws += NM * 2;   // fp16 [8][N][32]
    unsigned short* kvb  = (unsigned short*)ws; ws += NM * 4;   // [8][N][64] 16B-chunk k|v
    unsigned short* aggb = (unsigned short*)ws; ws += NM * 2;   // bf16 [N][256]
    float* wgt = (float*)ws;                    ws += (size_t)N_NODES * 32 * 4;

    dim3 blk(256);

    gemm_qkv_topk<<<dim3(3460), blk, 0, stream>>>(h, Wq, Wk, Wv, bq, bk, bv, ew,
                                                  qb, kvb, wgt, N_NODES);

    attn_shard<<<dim3(20000), blk, 0, stream>>>(qb, kvb, nbr, wgt, aggb);

    gemm_out<<<dim3(157, 2), blk, 0, stream>>>(aggb, Wo, bo, out, N_NODES);
}

// Round 10
// 176.431 us; speedup vs baseline: 1.3016x; 1.0454x over previous
//
#include <hip/hip_runtime.h>

#define N_NODES 20000
#define HID     256
#define DEG     32
#define TOPK    16
#define NRB     313      // ceil(20000/64) row-blocks of 64

typedef __attribute__((ext_vector_type(8))) short short8;
typedef __attribute__((ext_vector_type(4))) float f32x4;
typedef __attribute__((ext_vector_type(2))) _Float16 half2_t;

__device__ inline unsigned short f2bf(float f) {
    unsigned u = __float_as_uint(f);
    unsigned r = (u + 0x7FFFu + ((u >> 16) & 1u)) >> 16;  // RNE
    return (unsigned short)r;
}
__device__ inline float bf_lo(unsigned u) { return __uint_as_float(u << 16); }
__device__ inline float bf_hi(unsigned u) { return __uint_as_float(u & 0xFFFF0000u); }

__device__ inline unsigned short f2h(float f) {
    _Float16 h = (_Float16)f;               // v_cvt_f16_f32 (RNE)
    return __builtin_bit_cast(unsigned short, h);
}
__device__ inline half2_t u2h2(unsigned u) { return __builtin_bit_cast(half2_t, u); }

__device__ inline ushort4 cvt4(float4 f) {
    ushort4 o;
    o.x = f2bf(f.x); o.y = f2bf(f.y); o.z = f2bf(f.z); o.w = f2bf(f.w);
    return o;
}

// ---------------------------------------------------------------------------
// One-time weight conversion: 4 matrices fp32 -> bf16 (removes per-row-block
// redundant cvt from all GEMM K-loops; W slices stay L2-resident as bf16).
// ---------------------------------------------------------------------------
__global__ __launch_bounds__(256) void convert_w4(
    const float* __restrict__ a, const float* __restrict__ b,
    const float* __restrict__ c, const float* __restrict__ d,
    unsigned short* __restrict__ da, unsigned short* __restrict__ db,
    unsigned short* __restrict__ dc, unsigned short* __restrict__ dd)
{
    int y = blockIdx.y;
    const float* src = (y == 0) ? a : (y == 1) ? b : (y == 2) ? c : d;
    unsigned short* dst = (y == 0) ? da : (y == 1) ? db : (y == 2) ? dc : dd;
    int i = blockIdx.x * 256 + threadIdx.x;   // 16384 float4 per weight
    ((ushort4*)dst)[i] = cvt4(((const float4*)src)[i]);
}

// ---------------------------------------------------------------------------
// GEMM accumulate core: 64x128 tile, BK=64, 256 thr (4 waves), mfma 16x16x32.
// OPERAND-SWAPPED mfma(W-frag, A-frag): D col = node, D regs = 4 consecutive
// output cols -> vectorized epilogue. W bf16; A fp32 (AF32=1) or bf16.
// Wave w: rows wm=(w&1)*32 (2 tiles), cols wn=(w>>1)*64 (4 tiles) -> acc[2][4].
// ---------------------------------------------------------------------------
#define PADE 8
template<int AF32>
__device__ __forceinline__ void gemm_tile64(
    const void* __restrict__ Araw, const unsigned short* __restrict__ W,
    int M, int rowbase, int colbase, f32x4 acc[2][4])
{
    __shared__ unsigned short As[64][64 + PADE];
    __shared__ unsigned short Ws[128][64 + PADE];

    const int t    = threadIdx.x;
    const int lane = t & 63;
    const int wave = t >> 6;
    const int wm   = (wave & 1) * 32;
    const int wn   = (wave >> 1) * 64;

    const int lm = lane & 15;
    const int q8 = (lane >> 4) * 8;

    for (int k0 = 0; k0 < 256; k0 += 64) {
        // A tile: 64x64 -> 512 16B chunks, 2/thread
        #pragma unroll
        for (int c = 0; c < 2; ++c) {
            int idx = t + 256 * c;
            int row = idx >> 3;
            int col = (idx & 7) * 8;
            int grow = rowbase + row;
            if (AF32) {
                const float* A = (const float*)Araw;
                float4 f0 = make_float4(0.f, 0.f, 0.f, 0.f);
                float4 f1 = make_float4(0.f, 0.f, 0.f, 0.f);
                if (grow < M) {
                    f0 = *(const float4*)(A + (size_t)grow * 256 + k0 + col);
                    f1 = *(const float4*)(A + (size_t)grow * 256 + k0 + col + 4);
                }
                *(ushort4*)&As[row][col]     = cvt4(f0);
                *(ushort4*)&As[row][col + 4] = cvt4(f1);
            } else {
                const unsigned short* A = (const unsigned short*)Araw;
                uint4 av = make_uint4(0u, 0u, 0u, 0u);
                if (grow < M) av = *(const uint4*)(A + (size_t)grow * 256 + k0 + col);
                *(uint4*)&As[row][col] = av;
            }
        }
        // W tile: 128x64 -> 1024 16B chunks, 4/thread (bf16, no cvt)
        #pragma unroll
        for (int c = 0; c < 4; ++c) {
            int idx = t + 256 * c;
            int row = idx >> 3;
            int col = (idx & 7) * 8;
            uint4 wv = *(const uint4*)(W + (size_t)(colbase + row) * 256 + k0 + col);
            *(uint4*)&Ws[row][col] = wv;
        }
        __syncthreads();

        #pragma unroll
        for (int kk = 0; kk < 64; kk += 32) {
            short8 af[2], bfr[4];
            #pragma unroll
            for (int i = 0; i < 2; ++i)
                af[i] = *(const short8*)&As[wm + i * 16 + lm][kk + q8];
            #pragma unroll
            for (int j = 0; j < 4; ++j)
                bfr[j] = *(const short8*)&Ws[wn + j * 16 + lm][kk + q8];
            #pragma unroll
            for (int i = 0; i < 2; ++i)
                #pragma unroll
                for (int j = 0; j < 4; ++j)
                    acc[i][j] = __builtin_amdgcn_mfma_f32_16x16x32_bf16(
                        bfr[j], af[i], acc[i][j], 0, 0, 0);   // swapped operands
        }
        __syncthreads();
    }
}

// ---------------------------------------------------------------------------
// q/k/v projections + top-k, one dispatch.
//   blocks 0..1919: GEMM, XCD-pinned 64-row blocks (id&7), variant = (z, by).
//     q  -> fp16 head-major [8][N][32]
//     kv -> [8][N][64], 16B chunks: chunk c = {k[4c..4c+3] fp16, v[4c..4c+3] bf16}
//   blocks 1920..4419: top-16 edge-weight mask + normalize (8 nodes/block).
// ---------------------------------------------------------------------------
__global__ __launch_bounds__(256) void gemm_qkv_topk(
    const float* __restrict__ A,
    const unsigned short* __restrict__ Wq, const unsigned short* __restrict__ Wk,
    const unsigned short* __restrict__ Wv,
    const float* __restrict__ bq, const float* __restrict__ bk,
    const float* __restrict__ bv,
    const float* __restrict__ ew,
    unsigned short* __restrict__ Cq, unsigned short* __restrict__ kv,
    float* __restrict__ wgt, int M)
{
    const int id = blockIdx.x;
    const int t  = threadIdx.x;

    if (id >= 1920) {                     // ---- topk branch ----
        int n = (id - 1920) * 8 + (t >> 5);
        int lane = t & 31;
        float my = ew[n * 32 + lane];
        int cnt = 0;
        #pragma unroll
        for (int j = 0; j < 32; ++j) {
            float o = __shfl(my, j, 32);
            cnt += (o > my || (o == my && j < lane)) ? 1 : 0;
        }
        float w = (cnt < TOPK) ? my : 0.0f;
        float s = w;
        #pragma unroll
        for (int off = 16; off; off >>= 1) s += __shfl_xor(s, off, 32);
        wgt[n * 32 + lane] = w / (s + 1e-5f);
        return;
    }

    const int xcd     = id & 7;
    const int rest    = id >> 3;          // 0..239
    const int rowblk  = xcd + 8 * (rest / 6);
    const int variant = rest % 6;
    if (rowblk >= NRB) return;
    const int z  = variant >> 1;
    const int by = variant & 1;

    const unsigned short* W = (z == 0) ? Wq : (z == 1) ? Wk : Wv;
    const float* bias        = (z == 0) ? bq : (z == 1) ? bk : bv;

    f32x4 acc[2][4];
    #pragma unroll
    for (int i = 0; i < 2; ++i)
        #pragma unroll
        for (int j = 0; j < 4; ++j)
            acc[i][j] = (f32x4){0.f, 0.f, 0.f, 0.f};

    gemm_tile64<1>(A, W, M, rowblk * 64, by * 128, acc);

    const int lane = t & 63;
    const int wave = t >> 6;
    const int wm   = (wave & 1) * 32;
    const int wn   = (wave >> 1) * 64;
    const int lm   = lane & 15;
    const int lq   = lane >> 4;

    #pragma unroll
    for (int i = 0; i < 2; ++i) {
        int node = rowblk * 64 + wm + i * 16 + lm;
        if (node >= M) continue;
        #pragma unroll
        for (int j = 0; j < 4; ++j) {
            int col0 = by * 128 + wn + j * 16 + lq * 4;   // 4 consecutive cols
            float4 b4 = *(const float4*)(bias + col0);
            float x0 = acc[i][j][0] + b4.x;
            float x1 = acc[i][j][1] + b4.y;
            float x2 = acc[i][j][2] + b4.z;
            float x3 = acc[i][j][3] + b4.w;
            int hh = col0 >> 5, cc = col0 & 31;
            if (z == 0) {
                ushort4 o; o.x = f2h(x0); o.y = f2h(x1); o.z = f2h(x2); o.w = f2h(x3);
                *(ushort4*)(Cq + (size_t)hh * ((size_t)N_NODES * 32)
                               + (size_t)node * 32 + cc) = o;
            } else if (z == 1) {
                ushort4 o; o.x = f2h(x0); o.y = f2h(x1); o.z = f2h(x2); o.w = f2h(x3);
                *(ushort4*)(kv + (size_t)hh * ((size_t)N_NODES * 64)
                               + (size_t)node * 64 + (cc >> 2) * 8) = o;
            } else {
                ushort4 o; o.x = f2bf(x0); o.y = f2bf(x1); o.z = f2bf(x2); o.w = f2bf(x3);
                *(ushort4*)(kv + (size_t)hh * ((size_t)N_NODES * 64)
                               + (size_t)node * 64 + (cc >> 2) * 8 + 4) = o;
            }
        }
    }
}

// ---------------------------------------------------------------------------
// o-projection: A bf16 (agg), W bf16, fp32 out + fused leaky-relu.
// 64-row tiles, XCD-pinned (both col-halves of a row-block share an XCD).
// ---------------------------------------------------------------------------
__global__ __launch_bounds__(256) void gemm_out(
    const unsigned short* __restrict__ A, const unsigned short* __restrict__ W,
    const float* __restrict__ bias, float* __restrict__ out, int M)
{
    const int id     = blockIdx.x;
    const int xcd    = id & 7;
    const int rest   = id >> 3;           // 0..79
    const int rowblk = xcd + 8 * (rest >> 1);
    const int ch     = rest & 1;
    if (rowblk >= NRB) return;

    f32x4 acc[2][4];
    #pragma unroll
    for (int i = 0; i < 2; ++i)
        #pragma unroll
        for (int j = 0; j < 4; ++j)
            acc[i][j] = (f32x4){0.f, 0.f, 0.f, 0.f};

    gemm_tile64<0>(A, W, M, rowblk * 64, ch * 128, acc);

    const int lane = threadIdx.x & 63;
    const int wave = threadIdx.x >> 6;
    const int wm   = (wave & 1) * 32;
    const int wn   = (wave >> 1) * 64;
    const int lm   = lane & 15;
    const int lq   = lane >> 4;

    #pragma unroll
    for (int i = 0; i < 2; ++i) {
        int node = rowblk * 64 + wm + i * 16 + lm;
        if (node >= M) continue;
        #pragma unroll
        for (int j = 0; j < 4; ++j) {
            int col0 = ch * 128 + wn + j * 16 + lq * 4;
            float4 b4 = *(const float4*)(bias + col0);
            float4 o;
            o.x = acc[i][j][0] + b4.x;
            o.y = acc[i][j][1] + b4.y;
            o.z = acc[i][j][2] + b4.z;
            o.w = acc[i][j][3] + b4.w;
            o.x = (o.x >= 0.f) ? o.x : 0.01f * o.x;
            o.y = (o.y >= 0.f) ? o.y : 0.01f * o.y;
            o.z = (o.z >= 0.f) ? o.z : 0.01f * o.z;
            o.w = (o.w >= 0.f) ? o.w : 0.01f * o.w;
            *(float4*)(out + (size_t)node * 256 + col0) = o;
        }
    }
}

// ---------------------------------------------------------------------------
// Attention, head-sharded (head = blockIdx.x & 7 -> XCD-pinned shard).
// kv [8][N][64] in 16B chunks {4 k fp16 | 4 v bf16}; fully-coalesced gathers.
// Softmax in exp2 domain: z = score*w*(1/sqrt(32)*log2(e)), e = exp2(z-mx) —
// identical math to exp-softmax, one v_exp_f32 per logit. rcp for normalize.
// ---------------------------------------------------------------------------
__global__ __launch_bounds__(256) void attn_shard(
    const unsigned short* __restrict__ qh, const unsigned short* __restrict__ kv,
    const int* __restrict__ nbr, const float* __restrict__ wgt,
    unsigned short* __restrict__ agg)
{
    const int h    = blockIdx.x & 7;
    const int t    = threadIdx.x;
    const int lane = t & 31;
    const int n    = (blockIdx.x >> 3) * 8 + (t >> 5);

    const size_t hkv = (size_t)h * ((size_t)N_NODES * 64);
    const size_t hq  = (size_t)h * ((size_t)N_NODES * 32);

    const int   nbv = nbr[n * 32 + lane];
    const float w   = wgt[n * 32 + lane];

    const int cg = lane & 7;
    const int dg = lane >> 3;            // 0..3

    // neighbors this lane covers: dg + 4j; weight pre-scaled into exp2 domain
    int   nbj[8];
    float wj2[8];
    #pragma unroll
    for (int j = 0; j < 8; ++j) {
        nbj[j] = __shfl(nbv, dg + 4 * j, 32);
        wj2[j] = __shfl(w,   dg + 4 * j, 32) * 0.25500917211914f; // /sqrt(32)*log2e
    }

    // one fully-coalesced uint4 per neighbor: chunk cg = 4 k fp16 + 4 v bf16
    uint4 kvr[8];
    #pragma unroll
    for (int j = 0; j < 8; ++j)
        kvr[j] = *(const uint4*)(kv + hkv + (size_t)nbj[j] * 64 + cg * 8);

    // q chunk: 4 fp16 at cols 4cg..4cg+3 (broadcast across dg)
    uint2 qc = *(const uint2*)(qh + hq + (size_t)n * 32 + cg * 4);

    // partial scores (4 cols), reduce over cg
    float p[8];
    #pragma unroll
    for (int j = 0; j < 8; ++j) {
        float s = __builtin_amdgcn_fdot2(u2h2(kvr[j].x), u2h2(qc.x), 0.f, false);
        p[j]    = __builtin_amdgcn_fdot2(u2h2(kvr[j].y), u2h2(qc.y), s, false);
    }
    #pragma unroll
    for (int off = 1; off <= 4; off <<= 1)
        #pragma unroll
        for (int j = 0; j < 8; ++j)
            p[j] += __shfl_xor(p[j], off, 32);

    // logits in exp2 domain, softmax over 32 neighbors (8 local x 4 dg)
    #pragma unroll
    for (int j = 0; j < 8; ++j)
        p[j] = p[j] * wj2[j];

    float mx = p[0];
    #pragma unroll
    for (int j = 1; j < 8; ++j) mx = fmaxf(mx, p[j]);
    mx = fmaxf(mx, __shfl_xor(mx, 8, 32));
    mx = fmaxf(mx, __shfl_xor(mx, 16, 32));

    float ssum = 0.f;
    #pragma unroll
    for (int j = 0; j < 8; ++j) {
        p[j] = __builtin_amdgcn_exp2f(p[j] - mx);
        ssum += p[j];
    }
    ssum += __shfl_xor(ssum, 8, 32);
    ssum += __shfl_xor(ssum, 16, 32);
    const float inv = __builtin_amdgcn_rcpf(ssum);

    // v accumulate: cols 4cg..4cg+3, partial over dg then reduce (xor 8,16)
    float a0 = 0.f, a1 = 0.f, a2 = 0.f, a3 = 0.f;
    #pragma unroll
    for (int j = 0; j < 8; ++j) {
        float aw = p[j] * inv;
        a0 = fmaf(aw, bf_lo(kvr[j].z), a0);
        a1 = fmaf(aw, bf_hi(kvr[j].z), a1);
        a2 = fmaf(aw, bf_lo(kvr[j].w), a2);
        a3 = fmaf(aw, bf_hi(kvr[j].w), a3);
    }
    a0 += __shfl_xor(a0, 8, 32);  a0 += __shfl_xor(a0, 16, 32);
    a1 += __shfl_xor(a1, 8, 32);  a1 += __shfl_xor(a1, 16, 32);
    a2 += __shfl_xor(a2, 8, 32);  a2 += __shfl_xor(a2, 16, 32);
    a3 += __shfl_xor(a3, 8, 32);  a3 += __shfl_xor(a3, 16, 32);

    if (dg == 0) {
        ushort4 o;
        o.x = f2bf(a0); o.y = f2bf(a1); o.z = f2bf(a2); o.w = f2bf(a3);
        *(ushort4*)(agg + (size_t)n * 256 + h * 32 + cg * 4) = o;
    }
}

// ---------------------------------------------------------------------------
extern "C" void kernel_launch(void* const* d_in, const int* in_sizes, int n_in,
                              void* d_out, int out_size, void* d_ws, size_t ws_size,
                              hipStream_t stream)
{
    const float* h   = (const float*)d_in[0];
    const int*   nbr = (const int*)  d_in[1];
    const float* ew  = (const float*)d_in[2];
    const float* Wq  = (const float*)d_in[3];
    const float* bq  = (const float*)d_in[4];
    const float* Wk  = (const float*)d_in[5];
    const float* bk  = (const float*)d_in[6];
    const float* Wv  = (const float*)d_in[7];
    const float* bv  = (const float*)d_in[8];
    const float* Wo  = (const float*)d_in[9];
    const float* bo  = (const float*)d_in[10];
    float* out = (float*)d_out;

    const size_t NM = (size_t)N_NODES * HID;   // 5,120,000
    char* ws = (char*)d_ws;
    unsigned short* qb   = (unsigned short*)ws; ws += NM * 2;   // fp16 [8][N][32]
    unsigned short* kvb  = (unsigned short*)ws; ws += NM * 4;   // [8][N][64] 16B-chunk k|v
    unsigned short* aggb = (unsigned short*)ws; ws += NM * 2;   // bf16 [N][256]
    unsigned short* Wqb  = (unsigned short*)ws; ws += 65536 * 2;
    unsigned short* Wkb  = (unsigned short*)ws; ws += 65536 * 2;
    unsigned short* Wvb  = (unsigned short*)ws; ws += 65536 * 2;
    unsigned short* Wob  = (unsigned short*)ws; ws += 65536 * 2;
    float* wgt = (float*)ws;                    ws += (size_t)N_NODES * 32 * 4;

    dim3 blk(256);

    convert_w4<<<dim3(64, 4), blk, 0, stream>>>(Wq, Wk, Wv, Wo, Wqb, Wkb, Wvb, Wob);

    gemm_qkv_topk<<<dim3(4420), blk, 0, stream>>>(h, Wqb, Wkb, Wvb, bq, bk, bv, ew,
                                                  qb, kvb, wgt, N_NODES);

    attn_shard<<<dim3(20000), blk, 0, stream>>>(qb, kvb, nbr, wgt, aggb);

    gemm_out<<<dim3(640), blk, 0, stream>>>(aggb, Wob, bo, out, N_NODES);
}

// Round 11
// 170.123 us; speedup vs baseline: 1.3498x; 1.0371x over previous
//
#include <hip/hip_runtime.h>

#define N_NODES 20000
#define HID     256
#define DEG     32
#define TOPK    16
#define NRB     313      // ceil(20000/64) row-blocks of 64

typedef __attribute__((ext_vector_type(8))) short short8;
typedef __attribute__((ext_vector_type(4))) float f32x4;
typedef __attribute__((ext_vector_type(2))) _Float16 half2_t;

__device__ inline unsigned short f2bf(float f) {
    unsigned u = __float_as_uint(f);
    unsigned r = (u + 0x7FFFu + ((u >> 16) & 1u)) >> 16;  // RNE
    return (unsigned short)r;
}
__device__ inline float bf_lo(unsigned u) { return __uint_as_float(u << 16); }
__device__ inline float bf_hi(unsigned u) { return __uint_as_float(u & 0xFFFF0000u); }

__device__ inline unsigned short f2h(float f) {
    _Float16 h = (_Float16)f;               // v_cvt_f16_f32 (RNE)
    return __builtin_bit_cast(unsigned short, h);
}
__device__ inline half2_t u2h2(unsigned u) { return __builtin_bit_cast(half2_t, u); }

__device__ inline ushort4 cvt4(float4 f) {
    ushort4 o;
    o.x = f2bf(f.x); o.y = f2bf(f.y); o.z = f2bf(f.z); o.w = f2bf(f.w);
    return o;
}

// ---------------------------------------------------------------------------
// GEMM accumulate core: 64x128 tile, BK=64, 256 thr (4 waves), mfma 16x16x32.
// OPERAND-SWAPPED mfma(W-frag, A-frag): D col = node, D regs = 4 consecutive
// output cols -> vectorized epilogue. A fp32 (AF32=1) or bf16; W fp32
// (WF32=1, converted during staging) or bf16.
// ---------------------------------------------------------------------------
#define PADE 8
template<int AF32, int WF32>
__device__ __forceinline__ void gemm_tile64(
    const void* __restrict__ Araw, const void* __restrict__ Wraw,
    int M, int rowbase, int colbase, f32x4 acc[2][4])
{
    __shared__ unsigned short As[64][64 + PADE];
    __shared__ unsigned short Ws[128][64 + PADE];

    const int t    = threadIdx.x;
    const int lane = t & 63;
    const int wave = t >> 6;
    const int wm   = (wave & 1) * 32;
    const int wn   = (wave >> 1) * 64;

    const int lm = lane & 15;
    const int q8 = (lane >> 4) * 8;

    for (int k0 = 0; k0 < 256; k0 += 64) {
        // A tile: 64x64 -> 512 16B chunks, 2/thread
        #pragma unroll
        for (int c = 0; c < 2; ++c) {
            int idx = t + 256 * c;
            int row = idx >> 3;
            int col = (idx & 7) * 8;
            int grow = rowbase + row;
            if (AF32) {
                const float* A = (const float*)Araw;
                float4 f0 = make_float4(0.f, 0.f, 0.f, 0.f);
                float4 f1 = make_float4(0.f, 0.f, 0.f, 0.f);
                if (grow < M) {
                    f0 = *(const float4*)(A + (size_t)grow * 256 + k0 + col);
                    f1 = *(const float4*)(A + (size_t)grow * 256 + k0 + col + 4);
                }
                *(ushort4*)&As[row][col]     = cvt4(f0);
                *(ushort4*)&As[row][col + 4] = cvt4(f1);
            } else {
                const unsigned short* A = (const unsigned short*)Araw;
                uint4 av = make_uint4(0u, 0u, 0u, 0u);
                if (grow < M) av = *(const uint4*)(A + (size_t)grow * 256 + k0 + col);
                *(uint4*)&As[row][col] = av;
            }
        }
        // W tile: 128x64 -> 1024 16B chunks, 4/thread
        #pragma unroll
        for (int c = 0; c < 4; ++c) {
            int idx = t + 256 * c;
            int row = idx >> 3;
            int col = (idx & 7) * 8;
            if (WF32) {
                const float* W = (const float*)Wraw;
                float4 w0 = *(const float4*)(W + (size_t)(colbase + row) * 256 + k0 + col);
                float4 w1 = *(const float4*)(W + (size_t)(colbase + row) * 256 + k0 + col + 4);
                *(ushort4*)&Ws[row][col]     = cvt4(w0);
                *(ushort4*)&Ws[row][col + 4] = cvt4(w1);
            } else {
                const unsigned short* W = (const unsigned short*)Wraw;
                uint4 wv = *(const uint4*)(W + (size_t)(colbase + row) * 256 + k0 + col);
                *(uint4*)&Ws[row][col] = wv;
            }
        }
        __syncthreads();

        #pragma unroll
        for (int kk = 0; kk < 64; kk += 32) {
            short8 af[2], bfr[4];
            #pragma unroll
            for (int i = 0; i < 2; ++i)
                af[i] = *(const short8*)&As[wm + i * 16 + lm][kk + q8];
            #pragma unroll
            for (int j = 0; j < 4; ++j)
                bfr[j] = *(const short8*)&Ws[wn + j * 16 + lm][kk + q8];
            #pragma unroll
            for (int i = 0; i < 2; ++i)
                #pragma unroll
                for (int j = 0; j < 4; ++j)
                    acc[i][j] = __builtin_amdgcn_mfma_f32_16x16x32_bf16(
                        bfr[j], af[i], acc[i][j], 0, 0, 0);   // swapped operands
        }
        __syncthreads();
    }
}

// ---------------------------------------------------------------------------
// Dispatch 1: q/k/v projections + Wo convert + top-k, one kernel.
//   blocks 0..1919   : GEMM, XCD-pinned 64-row blocks (id&7), variant=(z,by),
//                      W fp32 converted inline during staging.
//     q  -> fp16 head-major [8][N][32]
//     kv -> [8][N][64], 16B chunks: chunk c = {k[4c..4c+3] fp16, v[4c..4c+3] bf16}
//   blocks 1920..1983: Wo fp32 -> bf16 (consumed by gemm_out, 2 dispatches later)
//   blocks 1984..4483: top-16 edge-weight mask + normalize (8 nodes/block)
// ---------------------------------------------------------------------------
__global__ __launch_bounds__(256) void gemm_qkv_topk(
    const float* __restrict__ A,
    const float* __restrict__ Wq, const float* __restrict__ Wk,
    const float* __restrict__ Wv, const float* __restrict__ Wo,
    const float* __restrict__ bq, const float* __restrict__ bk,
    const float* __restrict__ bv,
    const float* __restrict__ ew,
    unsigned short* __restrict__ Cq, unsigned short* __restrict__ kv,
    unsigned short* __restrict__ Wob, float* __restrict__ wgt, int M)
{
    const int id = blockIdx.x;
    const int t  = threadIdx.x;

    if (id >= 1984) {                     // ---- topk branch ----
        int n = (id - 1984) * 8 + (t >> 5);
        int lane = t & 31;
        float my = ew[n * 32 + lane];
        int cnt = 0;
        #pragma unroll
        for (int j = 0; j < 32; ++j) {
            float o = __shfl(my, j, 32);
            cnt += (o > my || (o == my && j < lane)) ? 1 : 0;
        }
        float w = (cnt < TOPK) ? my : 0.0f;
        float s = w;
        #pragma unroll
        for (int off = 16; off; off >>= 1) s += __shfl_xor(s, off, 32);
        wgt[n * 32 + lane] = w / (s + 1e-5f);
        return;
    }
    if (id >= 1920) {                     // ---- Wo convert branch ----
        int i = (id - 1920) * 256 + t;    // 16384 float4
        ((ushort4*)Wob)[i] = cvt4(((const float4*)Wo)[i]);
        return;
    }

    const int xcd     = id & 7;
    const int rest    = id >> 3;          // 0..239
    const int rowblk  = xcd + 8 * (rest / 6);
    const int variant = rest % 6;
    if (rowblk >= NRB) return;
    const int z  = variant >> 1;
    const int by = variant & 1;

    const float* W    = (z == 0) ? Wq : (z == 1) ? Wk : Wv;
    const float* bias = (z == 0) ? bq : (z == 1) ? bk : bv;

    f32x4 acc[2][4];
    #pragma unroll
    for (int i = 0; i < 2; ++i)
        #pragma unroll
        for (int j = 0; j < 4; ++j)
            acc[i][j] = (f32x4){0.f, 0.f, 0.f, 0.f};

    gemm_tile64<1, 1>(A, W, M, rowblk * 64, by * 128, acc);

    const int lane = t & 63;
    const int wave = t >> 6;
    const int wm   = (wave & 1) * 32;
    const int wn   = (wave >> 1) * 64;
    const int lm   = lane & 15;
    const int lq   = lane >> 4;

    #pragma unroll
    for (int i = 0; i < 2; ++i) {
        int node = rowblk * 64 + wm + i * 16 + lm;
        if (node >= M) continue;
        #pragma unroll
        for (int j = 0; j < 4; ++j) {
            int col0 = by * 128 + wn + j * 16 + lq * 4;   // 4 consecutive cols
            float4 b4 = *(const float4*)(bias + col0);
            float x0 = acc[i][j][0] + b4.x;
            float x1 = acc[i][j][1] + b4.y;
            float x2 = acc[i][j][2] + b4.z;
            float x3 = acc[i][j][3] + b4.w;
            int hh = col0 >> 5, cc = col0 & 31;
            if (z == 0) {
                ushort4 o; o.x = f2h(x0); o.y = f2h(x1); o.z = f2h(x2); o.w = f2h(x3);
                *(ushort4*)(Cq + (size_t)hh * ((size_t)N_NODES * 32)
                               + (size_t)node * 32 + cc) = o;
            } else if (z == 1) {
                ushort4 o; o.x = f2h(x0); o.y = f2h(x1); o.z = f2h(x2); o.w = f2h(x3);
                *(ushort4*)(kv + (size_t)hh * ((size_t)N_NODES * 64)
                               + (size_t)node * 64 + (cc >> 2) * 8) = o;
            } else {
                ushort4 o; o.x = f2bf(x0); o.y = f2bf(x1); o.z = f2bf(x2); o.w = f2bf(x3);
                *(ushort4*)(kv + (size_t)hh * ((size_t)N_NODES * 64)
                               + (size_t)node * 64 + (cc >> 2) * 8 + 4) = o;
            }
        }
    }
}

// ---------------------------------------------------------------------------
// Dispatch 3: o-projection. A bf16 (agg), W bf16 (pre-converted), fp32 out +
// fused leaky-relu. 64-row tiles, XCD-pinned.
// ---------------------------------------------------------------------------
__global__ __launch_bounds__(256) void gemm_out(
    const unsigned short* __restrict__ A, const unsigned short* __restrict__ W,
    const float* __restrict__ bias, float* __restrict__ out, int M)
{
    const int id     = blockIdx.x;
    const int xcd    = id & 7;
    const int rest   = id >> 3;           // 0..79
    const int rowblk = xcd + 8 * (rest >> 1);
    const int ch     = rest & 1;
    if (rowblk >= NRB) return;

    f32x4 acc[2][4];
    #pragma unroll
    for (int i = 0; i < 2; ++i)
        #pragma unroll
        for (int j = 0; j < 4; ++j)
            acc[i][j] = (f32x4){0.f, 0.f, 0.f, 0.f};

    gemm_tile64<0, 0>(A, W, M, rowblk * 64, ch * 128, acc);

    const int lane = threadIdx.x & 63;
    const int wave = threadIdx.x >> 6;
    const int wm   = (wave & 1) * 32;
    const int wn   = (wave >> 1) * 64;
    const int lm   = lane & 15;
    const int lq   = lane >> 4;

    #pragma unroll
    for (int i = 0; i < 2; ++i) {
        int node = rowblk * 64 + wm + i * 16 + lm;
        if (node >= M) continue;
        #pragma unroll
        for (int j = 0; j < 4; ++j) {
            int col0 = ch * 128 + wn + j * 16 + lq * 4;
            float4 b4 = *(const float4*)(bias + col0);
            float4 o;
            o.x = acc[i][j][0] + b4.x;
            o.y = acc[i][j][1] + b4.y;
            o.z = acc[i][j][2] + b4.z;
            o.w = acc[i][j][3] + b4.w;
            o.x = (o.x >= 0.f) ? o.x : 0.01f * o.x;
            o.y = (o.y >= 0.f) ? o.y : 0.01f * o.y;
            o.z = (o.z >= 0.f) ? o.z : 0.01f * o.z;
            o.w = (o.w >= 0.f) ? o.w : 0.01f * o.w;
            *(float4*)(out + (size_t)node * 256 + col0) = o;
        }
    }
}

// ---------------------------------------------------------------------------
// Dispatch 2: attention, head-sharded (head = blockIdx.x & 7 -> XCD L2 shard).
// kv [8][N][64] in 16B chunks {4 k fp16 | 4 v bf16}; fully-coalesced gathers.
// NEW: reduce-scatter dot reduction (7 shfl, not 24): after 3 halving rounds
// lane cg holds the COMPLETE score of neighbor dg+4*cg; softmax runs once per
// lane over the full 32-lane group (1 exp2); 8 broadcasts recover v-weights.
// ---------------------------------------------------------------------------
__global__ __launch_bounds__(256) void attn_shard(
    const unsigned short* __restrict__ qh, const unsigned short* __restrict__ kv,
    const int* __restrict__ nbr, const float* __restrict__ wgt,
    unsigned short* __restrict__ agg)
{
    const int h    = blockIdx.x & 7;
    const int t    = threadIdx.x;
    const int lane = t & 31;
    const int n    = (blockIdx.x >> 3) * 8 + (t >> 5);

    const size_t hkv = (size_t)h * ((size_t)N_NODES * 64);
    const size_t hq  = (size_t)h * ((size_t)N_NODES * 32);

    const int   nbv = nbr[n * 32 + lane];   // neighbor `lane`
    const float w   = wgt[n * 32 + lane];   // weight of neighbor `lane`

    const int cg = lane & 7;
    const int dg = lane >> 3;            // 0..3

    // neighbors this lane gathers: dg + 4j, j = 0..7
    int nbj[8];
    #pragma unroll
    for (int j = 0; j < 8; ++j)
        nbj[j] = __shfl(nbv, dg + 4 * j, 32);

    // one fully-coalesced uint4 per neighbor: chunk cg = 4 k fp16 + 4 v bf16
    uint4 kvr[8];
    #pragma unroll
    for (int j = 0; j < 8; ++j)
        kvr[j] = *(const uint4*)(kv + hkv + (size_t)nbj[j] * 64 + cg * 8);

    // q chunk: 4 fp16 at cols 4cg..4cg+3 (broadcast across dg)
    uint2 qc = *(const uint2*)(qh + hq + (size_t)n * 32 + cg * 4);

    // partial scores (this lane's 4 cols) for its 8 neighbors
    float p[8];
    #pragma unroll
    for (int j = 0; j < 8; ++j) {
        float s = __builtin_amdgcn_fdot2(u2h2(kvr[j].x), u2h2(qc.x), 0.f, false);
        p[j]    = __builtin_amdgcn_fdot2(u2h2(kvr[j].y), u2h2(qc.y), s, false);
    }

    // reduce-scatter over cg (xor 4,2,1): keep j-bits equal to cg-bits.
    // Final: lane holds full dot of neighbor m = dg + 4*cg.
    const bool b4 = (cg & 4) != 0;
    float q4[4];
    #pragma unroll
    for (int jj = 0; jj < 4; ++jj) {
        float snd = b4 ? p[jj] : p[jj + 4];
        float kp  = b4 ? p[jj + 4] : p[jj];
        q4[jj] = kp + __shfl_xor(snd, 4, 32);
    }
    const bool b2 = (cg & 2) != 0;
    float q2[2];
    #pragma unroll
    for (int jj = 0; jj < 2; ++jj) {
        float snd = b2 ? q4[jj] : q4[jj + 2];
        float kp  = b2 ? q4[jj + 2] : q4[jj];
        q2[jj] = kp + __shfl_xor(snd, 2, 32);
    }
    const bool b1 = (cg & 1) != 0;
    {
        float snd = b1 ? q2[0] : q2[1];
        float kp  = b1 ? q2[1] : q2[0];
        q2[0] = kp + __shfl_xor(snd, 1, 32);
    }
    const float sc = q2[0];                         // dot of neighbor dg+4*cg
    const float wm = __shfl(w, dg + 4 * cg, 32);    // its edge weight

    // logit in exp2 domain; softmax over all 32 lanes (= all 32 neighbors)
    float z = sc * wm * 0.25500917211914f;          // / sqrt(32) * log2(e)
    float mx = z;
    #pragma unroll
    for (int off = 1; off <= 16; off <<= 1)
        mx = fmaxf(mx, __shfl_xor(mx, off, 32));
    float e = __builtin_amdgcn_exp2f(z - mx);
    float ssum = e;
    #pragma unroll
    for (int off = 1; off <= 16; off <<= 1)
        ssum += __shfl_xor(ssum, off, 32);
    const float aw = e * __builtin_amdgcn_rcpf(ssum);   // attn weight of nbr dg+4cg

    // v accumulate: cols 4cg..4cg+3; aw of neighbor dg+4j lives at lane 8*dg+j
    float a0 = 0.f, a1 = 0.f, a2 = 0.f, a3 = 0.f;
    #pragma unroll
    for (int j = 0; j < 8; ++j) {
        float awv = __shfl(aw, 8 * dg + j, 32);
        a0 = fmaf(awv, bf_lo(kvr[j].z), a0);
        a1 = fmaf(awv, bf_hi(kvr[j].z), a1);
        a2 = fmaf(awv, bf_lo(kvr[j].w), a2);
        a3 = fmaf(awv, bf_hi(kvr[j].w), a3);
    }
    a0 += __shfl_xor(a0, 8, 32);  a0 += __shfl_xor(a0, 16, 32);
    a1 += __shfl_xor(a1, 8, 32);  a1 += __shfl_xor(a1, 16, 32);
    a2 += __shfl_xor(a2, 8, 32);  a2 += __shfl_xor(a2, 16, 32);
    a3 += __shfl_xor(a3, 8, 32);  a3 += __shfl_xor(a3, 16, 32);

    if (dg == 0) {
        ushort4 o;
        o.x = f2bf(a0); o.y = f2bf(a1); o.z = f2bf(a2); o.w = f2bf(a3);
        *(ushort4*)(agg + (size_t)n * 256 + h * 32 + cg * 4) = o;
    }
}

// ---------------------------------------------------------------------------
extern "C" void kernel_launch(void* const* d_in, const int* in_sizes, int n_in,
                              void* d_out, int out_size, void* d_ws, size_t ws_size,
                              hipStream_t stream)
{
    const float* h   = (const float*)d_in[0];
    const int*   nbr = (const int*)  d_in[1];
    const float* ew  = (const float*)d_in[2];
    const float* Wq  = (const float*)d_in[3];
    const float* bq  = (const float*)d_in[4];
    const float* Wk  = (const float*)d_in[5];
    const float* bk  = (const float*)d_in[6];
    const float* Wv  = (const float*)d_in[7];
    const float* bv  = (const float*)d_in[8];
    const float* Wo  = (const float*)d_in[9];
    const float* bo  = (const float*)d_in[10];
    float* out = (float*)d_out;

    const size_t NM = (size_t)N_NODES * HID;   // 5,120,000
    char* ws = (char*)d_ws;
    unsigned short* qb   = (unsigned short*)ws; ws += NM * 2;   // fp16 [8][N][32]
    unsigned short* kvb  = (unsigned short*)ws; ws += NM * 4;   // [8][N][64] 16B-chunk k|v
    unsigned short* aggb = (unsigned short*)ws; ws += NM * 2;   // bf16 [N][256]
    unsigned short* Wob  = (unsigned short*)ws; ws += 65536 * 2;
    float* wgt = (float*)ws;                    ws += (size_t)N_NODES * 32 * 4;

    dim3 blk(256);

    gemm_qkv_topk<<<dim3(4484), blk, 0, stream>>>(h, Wq, Wk, Wv, Wo, bq, bk, bv, ew,
                                                  qb, kvb, Wob, wgt, N_NODES);

    attn_shard<<<dim3(20000), blk, 0, stream>>>(qb, kvb, nbr, wgt, aggb);

    gemm_out<<<dim3(640), blk, 0, stream>>>(aggb, Wob, bo, out, N_NODES);
}